// Round 3
// baseline (268.037 us; speedup 1.0000x reference)
//
#include <hip/hip_runtime.h>
#include <hip/hip_bf16.h>

// Dense FFN: out = relu(x @ w1 + b1) @ w2 + b2
// x  [8192,1024] f32, w1 [1024,4096] f32, b1 [4096] f32,
// w2 [4096,1024] f32, b2 [1024] f32, out [8192,1024] f32.
// R3: double-buffered LDS K-loop (loads for t+1 in flight during compute of
// t, so the barrier's vmcnt(0) drain overlaps MFMA) + XCD-aware block
// swizzle (A-strip stays in one XCD's L2) + fused prep dispatch.

typedef __bf16 bf16;
typedef __bf16 bf16x4 __attribute__((ext_vector_type(4)));
typedef __bf16 bf16x8 __attribute__((ext_vector_type(8)));
typedef float  f32x4  __attribute__((ext_vector_type(4)));

#define BM 128
#define BN 128
#define BK 64

__device__ __forceinline__ void gload_lds16(const bf16* g, bf16* l) {
    __builtin_amdgcn_global_load_lds(
        (const __attribute__((address_space(1))) unsigned int*)g,
        (__attribute__((address_space(3))) unsigned int*)l,
        16, 0, 0);
}

// ---------------------------------------------------------------------------
// fused prep: cast x -> bf16 ; transpose+cast w1, w2 -> [N][K] bf16.
// grid = 8192 (cast) + 1024 (w1) + 1024 (w2) blocks of 256.
__device__ __forceinline__ void transpose_tile(
    const float* __restrict__ in, bf16* __restrict__ out,
    int K, int N, int bx, int by, int t, bf16 (*tile)[72])
{
    const int k0 = by * 64;
    const int n0 = bx * 64;
    const int lr = t >> 4;          // 0..15
    const int lc = (t & 15) << 2;   // 0,4,..60
#pragma unroll
    for (int p = 0; p < 4; ++p) {
        int k = p * 16 + lr;
        float4 v = *(const float4*)(in + (size_t)(k0 + k) * N + n0 + lc);
        tile[lc + 0][k] = (bf16)v.x;
        tile[lc + 1][k] = (bf16)v.y;
        tile[lc + 2][k] = (bf16)v.z;
        tile[lc + 3][k] = (bf16)v.w;
    }
    __syncthreads();
    const int wr = t >> 3;          // 0..31
    const int wc = (t & 7) << 3;    // 0,8,..56
#pragma unroll
    for (int p = 0; p < 2; ++p) {
        int n = p * 32 + wr;
        *(bf16x8*)(out + (size_t)(n0 + n) * K + k0 + wc) =
            *(const bf16x8*)&tile[n][wc];
    }
}

__global__ __launch_bounds__(256) void prep(
    const float* __restrict__ x,  bf16* __restrict__ xb,
    const float* __restrict__ w1, bf16* __restrict__ w1t,
    const float* __restrict__ w2, bf16* __restrict__ w2t)
{
    __shared__ __align__(16) bf16 tile[64][72];
    const int b = blockIdx.x;
    const int t = threadIdx.x;
    if (b < 8192) {                      // cast x: 4 f32/thread
        int i = b * 256 + t;
        float4 v = ((const float4*)x)[i];
        bf16x4 o;
        o.x = (bf16)v.x; o.y = (bf16)v.y; o.z = (bf16)v.z; o.w = (bf16)v.w;
        ((bf16x4*)xb)[i] = o;
    } else if (b < 9216) {               // w1 [1024][4096] -> w1t [4096][1024]
        int b2 = b - 8192;
        transpose_tile(w1, w1t, 1024, 4096, b2 & 63, b2 >> 6, t, tile);
    } else {                             // w2 [4096][1024] -> w2t [1024][4096]
        int b2 = b - 9216;
        transpose_tile(w2, w2t, 4096, 1024, b2 & 15, b2 >> 4, t, tile);
    }
}

// ---------------------------------------------------------------------------
// C[m][n] = sum_k A[m][k] * Bt[n][k]  (+bias, opt relu)
// A [M][K] bf16, Bt [N][K] bf16.  Block = 256 thr = 4 waves, tile 128x128,
// BK=64, double-buffered LDS.  16x16x32 bf16 MFMA, zero bank conflicts via
// chunk XOR swizzle (c ^ (row&7)) applied on the global side of
// global_load_lds.  1-D grid, XCD-aware decode: xcd = lid&7, x fastest.
template <int FUSE_RELU_BF16>
__global__ __launch_bounds__(256, 2) void gemm_bt(
    const bf16* __restrict__ A, const bf16* __restrict__ Bt,
    const float* __restrict__ bias, void* __restrict__ Cout,
    int M, int N, int K, int nx)
{
    __shared__ __align__(16) bf16 As[2][BM * BK];
    __shared__ __align__(16) bf16 Bs[2][BN * BK];

    // swizzled block decode: M-strips striped across XCDs, N fastest per strip
    const int lid = blockIdx.x;
    const int xcd = lid & 7;
    const int j   = lid >> 3;
    const int bx  = j % nx;
    const int by  = (j / nx) * 8 + xcd;

    const int tid  = threadIdx.x;
    const int wave = tid >> 6;
    const int lane = tid & 63;

    // staging: each gload covers 8 rows x 64 elems (8 lanes/row, 16B/lane)
    const int l8  = lane >> 3;           // row within 8-row group
    const int c8  = lane & 7;            // LDS chunk slot
    const int swc = (c8 ^ l8) << 3;      // swizzled global chunk offset
    const size_t K_ = (size_t)K;

    const bf16* gA[4]; const bf16* gB[4];
#pragma unroll
    for (int g = 0; g < 4; ++g) {
        const int rr = wave * 32 + g * 8 + l8;
        gA[g] = A  + ((size_t)by * BM + rr) * K_ + swc;
        gB[g] = Bt + ((size_t)bx * BN + rr) * K_ + swc;
    }
    const int lofs = (wave * 32) * BK + lane * 8;   // LDS dest, per 8-row group

    const int wm   = (wave >> 1) << 6;
    const int wn   = (wave & 1) << 6;
    const int quad = lane >> 4;
    const int r    = lane & 15;
    const int r7   = lane & 7;

    f32x4 acc[4][4] = {};

    // ---- stage tile into buf, advance pointers
    auto stage = [&](int buf) {
#pragma unroll
        for (int g = 0; g < 4; ++g) {
            gload_lds16(gA[g], &As[buf][lofs + g * (8 * BK)]);
            gload_lds16(gB[g], &Bs[buf][lofs + g * (8 * BK)]);
            gA[g] += BK; gB[g] += BK;
        }
    };
    // ---- 32 MFMAs from buf
    auto compute = [&](int buf) {
#pragma unroll
        for (int h = 0; h < 2; ++h) {
            const int ch = ((h * 4 + quad) ^ r7) << 3;
            bf16x8 af[4], bfr[4];
#pragma unroll
            for (int i = 0; i < 4; ++i)
                af[i] = *(const bf16x8*)&As[buf][(wm + i * 16 + r) * BK + ch];
#pragma unroll
            for (int jj = 0; jj < 4; ++jj)
                bfr[jj] = *(const bf16x8*)&Bs[buf][(wn + jj * 16 + r) * BK + ch];
#pragma unroll
            for (int i = 0; i < 4; ++i)
#pragma unroll
                for (int jj = 0; jj < 4; ++jj)
                    acc[i][jj] = __builtin_amdgcn_mfma_f32_16x16x32_bf16(
                        af[i], bfr[jj], acc[i][jj], 0, 0, 0);
        }
    };

    const int T = K / BK;   // 16 or 64, always even
    stage(0);
    for (int t = 0; t < T; t += 2) {
        __syncthreads();          // buf0 (tile t) resident
        stage(1);                 // tile t+1 in flight during compute
        compute(0);
        __syncthreads();          // buf1 (tile t+1) resident
        if (t + 2 < T) stage(0);  // tile t+2 in flight
        compute(1);
    }

    // epilogue: C/D layout col = lane&15, row = quad*4 + reg
    const int m_base = by * BM + wm + quad * 4;
    const int n_base = bx * BN + wn + r;
    float bv[4];
#pragma unroll
    for (int jj = 0; jj < 4; ++jj) bv[jj] = bias[n_base + jj * 16];

    if (FUSE_RELU_BF16) {
        bf16* Cb = (bf16*)Cout;
#pragma unroll
        for (int i = 0; i < 4; ++i) {
#pragma unroll
            for (int p = 0; p < 4; ++p) {
                size_t row = (size_t)(m_base + i * 16 + p) * (size_t)N;
#pragma unroll
                for (int jj = 0; jj < 4; ++jj) {
                    float v = acc[i][jj][p] + bv[jj];
                    v = v > 0.f ? v : 0.f;
                    Cb[row + n_base + jj * 16] = (bf16)v;
                }
            }
        }
    } else {
        float* Cf = (float*)Cout;
#pragma unroll
        for (int i = 0; i < 4; ++i) {
#pragma unroll
            for (int p = 0; p < 4; ++p) {
                size_t row = (size_t)(m_base + i * 16 + p) * (size_t)N;
#pragma unroll
                for (int jj = 0; jj < 4; ++jj) {
                    Cf[row + n_base + jj * 16] = acc[i][jj][p] + bv[jj];
                }
            }
        }
    }
}

// ---------------------------------------------------------------------------
extern "C" void kernel_launch(void* const* d_in, const int* in_sizes, int n_in,
                              void* d_out, int out_size, void* d_ws, size_t ws_size,
                              hipStream_t stream)
{
    const float* x  = (const float*)d_in[0];  // [8192,1024]
    const float* w1 = (const float*)d_in[1];  // [1024,4096]
    const float* b1 = (const float*)d_in[2];  // [4096]
    const float* w2 = (const float*)d_in[3];  // [4096,1024]
    const float* b2 = (const float*)d_in[4];  // [1024]
    float* out = (float*)d_out;               // [8192,1024]

    const int M = 8192, D = 1024, W = 4096;

    char* ws = (char*)d_ws;
    bf16* xb  = (bf16*)(ws);                           // 16 MiB: [8192,1024]
    bf16* w1t = (bf16*)(ws + (size_t)(16 << 20));      //  8 MiB: [4096,1024]
    bf16* w2t = (bf16*)(ws + (size_t)(24 << 20));      //  8 MiB: [1024,4096]
    bf16* h   = (bf16*)(ws + (size_t)(32 << 20));      // 64 MiB: [8192,4096]

    // 1. fused prep: cast x, transpose+cast w1 & w2
    prep<<<8192 + 1024 + 1024, 256, 0, stream>>>(x, xb, w1, w1t, w2, w2t);

    // 2. h = relu(xb @ w1 + b1), bf16  [M][W]
    gemm_bt<1><<<(W / BN) * (M / BM), 256, 0, stream>>>(
        xb, w1t, b1, (void*)h, M, W, D, W / BN);

    // 3. out = h @ w2 + b2, f32  [M][D]
    gemm_bt<0><<<(D / BN) * (M / BM), 256, 0, stream>>>(
        h, w2t, b2, (void*)out, M, D, W, D / BN);
}

// Round 4
// 263.565 us; speedup vs baseline: 1.0170x; 1.0170x over previous
//
#include <hip/hip_runtime.h>
#include <hip/hip_bf16.h>

// Dense FFN: out = relu(x @ w1 + b1) @ w2 + b2
// x  [8192,1024] f32, w1 [1024,4096] f32, b1 [4096] f32,
// w2 [4096,1024] f32, b2 [1024] f32, out [8192,1024] f32.
// R4: LDS-bandwidth is the measured bottleneck (R2: both GEMMs = 85.7us at
// equal LDS traffic despite different occupancy).  Raise FLOP/LDS-byte with
// a 256x128 block tile (wave-tile 128x64, acc 128 VGPRs).  Revert R3's
// double-buffer (regressed: occupancy loss > overlap gain); keep the
// single-buffer 2-barrier loop, zero-conflict XOR chunk swizzle, XCD-aware
// block swizzle (FETCH 266->140MB in R3), fused prep.

typedef __bf16 bf16;
typedef __bf16 bf16x4 __attribute__((ext_vector_type(4)));
typedef __bf16 bf16x8 __attribute__((ext_vector_type(8)));
typedef float  f32x4  __attribute__((ext_vector_type(4)));

#define BM 256
#define BN 128
#define BK 64

__device__ __forceinline__ void gload_lds16(const bf16* g, bf16* l) {
    __builtin_amdgcn_global_load_lds(
        (const __attribute__((address_space(1))) unsigned int*)g,
        (__attribute__((address_space(3))) unsigned int*)l,
        16, 0, 0);
}

// ---------------------------------------------------------------------------
// fused prep: cast x -> bf16 ; transpose+cast w1, w2 -> [N][K] bf16.
__device__ __forceinline__ void transpose_tile(
    const float* __restrict__ in, bf16* __restrict__ out,
    int K, int N, int bx, int by, int t, bf16 (*tile)[72])
{
    const int k0 = by * 64;
    const int n0 = bx * 64;
    const int lr = t >> 4;          // 0..15
    const int lc = (t & 15) << 2;   // 0,4,..60
#pragma unroll
    for (int p = 0; p < 4; ++p) {
        int k = p * 16 + lr;
        float4 v = *(const float4*)(in + (size_t)(k0 + k) * N + n0 + lc);
        tile[lc + 0][k] = (bf16)v.x;
        tile[lc + 1][k] = (bf16)v.y;
        tile[lc + 2][k] = (bf16)v.z;
        tile[lc + 3][k] = (bf16)v.w;
    }
    __syncthreads();
    const int wr = t >> 3;          // 0..31
    const int wc = (t & 7) << 3;    // 0,8,..56
#pragma unroll
    for (int p = 0; p < 2; ++p) {
        int n = p * 32 + wr;
        *(bf16x8*)(out + (size_t)(n0 + n) * K + k0 + wc) =
            *(const bf16x8*)&tile[n][wc];
    }
}

__global__ __launch_bounds__(256) void prep(
    const float* __restrict__ x,  bf16* __restrict__ xb,
    const float* __restrict__ w1, bf16* __restrict__ w1t,
    const float* __restrict__ w2, bf16* __restrict__ w2t)
{
    __shared__ __align__(16) bf16 tile[64][72];
    const int b = blockIdx.x;
    const int t = threadIdx.x;
    if (b < 8192) {                      // cast x: 4 f32/thread
        int i = b * 256 + t;
        float4 v = ((const float4*)x)[i];
        bf16x4 o;
        o.x = (bf16)v.x; o.y = (bf16)v.y; o.z = (bf16)v.z; o.w = (bf16)v.w;
        ((bf16x4*)xb)[i] = o;
    } else if (b < 9216) {               // w1 [1024][4096] -> w1t [4096][1024]
        int b2 = b - 8192;
        transpose_tile(w1, w1t, 1024, 4096, b2 & 63, b2 >> 6, t, tile);
    } else {                             // w2 [4096][1024] -> w2t [1024][4096]
        int b2 = b - 9216;
        transpose_tile(w2, w2t, 4096, 1024, b2 & 15, b2 >> 4, t, tile);
    }
}

// ---------------------------------------------------------------------------
// C[m][n] = sum_k A[m][k] * Bt[n][k]  (+bias, opt relu)
// A [M][K] bf16, Bt [N][K] bf16.  Block = 256 thr = 4 waves, tile 256x128,
// BK=64.  Waves 2x2, wave-tile 128x64 (8x4 frags of 16x16x32 bf16 MFMA).
// LDS: row r stores chunk slot c = global_chunk ^ (r&7) (swizzle applied on
// the GLOBAL side of global_load_lds) -> fragment reads hit the b128 bank
// floor (0 conflicts, verified R2).  1-D grid, XCD decode: xcd=lid&7.
template <int FUSE_RELU_BF16>
__global__ __launch_bounds__(256, 2) void gemm_bt(
    const bf16* __restrict__ A, const bf16* __restrict__ Bt,
    const float* __restrict__ bias, void* __restrict__ Cout,
    int M, int N, int K, int nx)
{
    __shared__ __align__(16) bf16 As[BM * BK];   // 32 KiB
    __shared__ __align__(16) bf16 Bs[BN * BK];   // 16 KiB

    // XCD-aware block decode: M-strips striped across XCDs, N fastest
    const int lid = blockIdx.x;
    const int xcd = lid & 7;
    const int j   = lid >> 3;
    const int bx  = j % nx;
    const int by  = (j / nx) * 8 + xcd;

    const int tid  = threadIdx.x;
    const int wave = tid >> 6;
    const int lane = tid & 63;

    // staging: each gload covers 8 rows x 64 elems (8 lanes/row, 16B/lane)
    const int l8  = lane >> 3;           // row within 8-row group
    const int c8  = lane & 7;            // LDS chunk slot
    const int swc = (c8 ^ l8) << 3;      // swizzled global chunk offset
    const size_t K_ = (size_t)K;

    // wave w stages A rows [w*64, w*64+64) and B rows [w*32, w*32+32)
    const bf16* gA[8]; const bf16* gB[4];
#pragma unroll
    for (int g = 0; g < 8; ++g)
        gA[g] = A + ((size_t)by * BM + wave * 64 + g * 8 + l8) * K_ + swc;
#pragma unroll
    for (int g = 0; g < 4; ++g)
        gB[g] = Bt + ((size_t)bx * BN + wave * 32 + g * 8 + l8) * K_ + swc;
    bf16* lA0 = &As[(wave * 64) * BK] + lane * 8;
    bf16* lB0 = &Bs[(wave * 32) * BK] + lane * 8;

    const int wm   = (wave >> 1) << 7;   // 0 or 128
    const int wn   = (wave & 1) << 6;    // 0 or 64
    const int quad = lane >> 4;
    const int r    = lane & 15;
    const int r7   = lane & 7;

    f32x4 acc[8][4] = {};

    for (int k0 = 0; k0 < K; k0 += BK) {
        __syncthreads();
#pragma unroll
        for (int g = 0; g < 8; ++g) {
            gload_lds16(gA[g], lA0 + g * (8 * BK));
            gA[g] += BK;
        }
#pragma unroll
        for (int g = 0; g < 4; ++g) {
            gload_lds16(gB[g], lB0 + g * (8 * BK));
            gB[g] += BK;
        }
        __syncthreads();

#pragma unroll
        for (int h = 0; h < 2; ++h) {
            const int ch = ((h * 4 + quad) ^ r7) << 3;   // swizzled chunk
            bf16x8 bfr[4];
#pragma unroll
            for (int jj = 0; jj < 4; ++jj)
                bfr[jj] = *(const bf16x8*)&Bs[(wn + jj * 16 + r) * BK + ch];
#pragma unroll
            for (int i = 0; i < 8; ++i) {
                bf16x8 af = *(const bf16x8*)&As[(wm + i * 16 + r) * BK + ch];
#pragma unroll
                for (int jj = 0; jj < 4; ++jj)
                    acc[i][jj] = __builtin_amdgcn_mfma_f32_16x16x32_bf16(
                        af, bfr[jj], acc[i][jj], 0, 0, 0);
            }
        }
    }

    // epilogue: C/D layout col = lane&15, row = quad*4 + reg
    const int m_base = by * BM + wm + quad * 4;
    const int n_base = bx * BN + wn + r;
    float bv[4];
#pragma unroll
    for (int jj = 0; jj < 4; ++jj) bv[jj] = bias[n_base + jj * 16];

    if (FUSE_RELU_BF16) {
        bf16* Cb = (bf16*)Cout;
#pragma unroll
        for (int i = 0; i < 8; ++i) {
#pragma unroll
            for (int p = 0; p < 4; ++p) {
                size_t row = (size_t)(m_base + i * 16 + p) * (size_t)N;
#pragma unroll
                for (int jj = 0; jj < 4; ++jj) {
                    float v = acc[i][jj][p] + bv[jj];
                    v = v > 0.f ? v : 0.f;
                    Cb[row + n_base + jj * 16] = (bf16)v;
                }
            }
        }
    } else {
        float* Cf = (float*)Cout;
#pragma unroll
        for (int i = 0; i < 8; ++i) {
#pragma unroll
            for (int p = 0; p < 4; ++p) {
                size_t row = (size_t)(m_base + i * 16 + p) * (size_t)N;
#pragma unroll
                for (int jj = 0; jj < 4; ++jj) {
                    Cf[row + n_base + jj * 16] = acc[i][jj][p] + bv[jj];
                }
            }
        }
    }
}

// ---------------------------------------------------------------------------
extern "C" void kernel_launch(void* const* d_in, const int* in_sizes, int n_in,
                              void* d_out, int out_size, void* d_ws, size_t ws_size,
                              hipStream_t stream)
{
    const float* x  = (const float*)d_in[0];  // [8192,1024]
    const float* w1 = (const float*)d_in[1];  // [1024,4096]
    const float* b1 = (const float*)d_in[2];  // [4096]
    const float* w2 = (const float*)d_in[3];  // [4096,1024]
    const float* b2 = (const float*)d_in[4];  // [1024]
    float* out = (float*)d_out;               // [8192,1024]

    const int M = 8192, D = 1024, W = 4096;

    char* ws = (char*)d_ws;
    bf16* xb  = (bf16*)(ws);                           // 16 MiB: [8192,1024]
    bf16* w1t = (bf16*)(ws + (size_t)(16 << 20));      //  8 MiB: [4096,1024]
    bf16* w2t = (bf16*)(ws + (size_t)(24 << 20));      //  8 MiB: [1024,4096]
    bf16* h   = (bf16*)(ws + (size_t)(32 << 20));      // 64 MiB: [8192,4096]

    // 1. fused prep: cast x, transpose+cast w1 & w2
    prep<<<8192 + 1024 + 1024, 256, 0, stream>>>(x, xb, w1, w1t, w2, w2t);

    // 2. h = relu(xb @ w1 + b1), bf16  [M][W]   grid 32x32 = 1024
    gemm_bt<1><<<(W / BN) * (M / BM), 256, 0, stream>>>(
        xb, w1t, b1, (void*)h, M, W, D, W / BN);

    // 3. out = h @ w2 + b2, f32  [M][D]         grid 8x32 = 256
    gemm_bt<0><<<(D / BN) * (M / BM), 256, 0, stream>>>(
        h, w2t, b2, (void*)out, M, D, W, D / BN);
}